// Round 3
// baseline (998.626 us; speedup 1.0000x reference)
//
#include <hip/hip_runtime.h>
#include <cstdint>
#include <cstddef>

#define DEVI __device__ __forceinline__

typedef __attribute__((ext_vector_type(8))) short bf16x8;
typedef __attribute__((ext_vector_type(4))) float f32x4;

DEVI unsigned short f2bf(float f) {
  unsigned u = __builtin_bit_cast(unsigned, f);
  u += 0x7fffu + ((u >> 16) & 1u);
  return (unsigned short)(u >> 16);
}

DEVI f32x4 mfma16(bf16x8 a, bf16x8 b, f32x4 c) {
  return __builtin_amdgcn_mfma_f32_16x16x32_bf16(a, b, c, 0, 0, 0);
}

#define GLD16(g, l) __builtin_amdgcn_global_load_lds( \
    (const __attribute__((address_space(1))) unsigned int*)(g), \
    (__attribute__((address_space(3))) unsigned int*)(l), 16, 0, 0)

// ---------------------------------------------------------------------------
// All weight transposes in ONE launch: W (K x N, fp32) -> Wt (N x K, bf16),
// concatenated. 4x 147456 + 2x 589824 = 1769472 = 6912 * 256 exactly.
__global__ __launch_bounds__(256)
void wtrans_all(const float* __restrict__ Wq, const float* __restrict__ Wk,
                const float* __restrict__ Wv, const float* __restrict__ Wo,
                const float* __restrict__ W1, const float* __restrict__ W2,
                unsigned short* __restrict__ out) {
  int e = blockIdx.x * 256 + threadIdx.x;
  const float* W;
  int K, N, off;
  if (e < 147456) { W = Wq; K = 384; N = 384; off = 0; }
  else if (e < 294912) { W = Wk; K = 384; N = 384; off = 147456; }
  else if (e < 442368) { W = Wv; K = 384; N = 384; off = 294912; }
  else if (e < 589824) { W = Wo; K = 384; N = 384; off = 442368; }
  else if (e < 1179648) { W = W1; K = 384; N = 1536; off = 589824; }
  else { W = W2; K = 1536; N = 384; off = 1179648; }
  int le = e - off;
  int n = le / K, k = le - n * K;
  out[e] = f2bf(W[(size_t)k * N + n]);
}

// ---------------------------------------------------------------------------
// Fused LN(q)/LN(km)/LN(kp) + roll(-2,-2) + window partition, for one chunk
// of 2048 windows (32768 tokens). One wave per destination window-token.
//   q_ln : (32768, 384) local row dl
//   kv_ln: (2048*32, 384) local rows wl*32+t (km), wl*32+16+t (kp)
__global__ __launch_bounds__(256)
void ln_win_k(const float* __restrict__ xm, const float* __restrict__ xp,
              const float* __restrict__ gq, const float* __restrict__ bq,
              const float* __restrict__ gkm, const float* __restrict__ bkm,
              const float* __restrict__ gkp, const float* __restrict__ bkp,
              unsigned short* __restrict__ q_ln,
              unsigned short* __restrict__ kv_ln, int wbase) {
  const int dl = blockIdx.x * 4 + (threadIdx.x >> 6);  // 0..32767
  const int l = threadIdx.x & 63;
  const int wl = dl >> 4, t = dl & 15;
  const int w = wbase + wl;
  const int b = w >> 8, wi = w & 255;
  const int hs = (((wi >> 4) << 2) + (t >> 2) + 2) & 63;
  const int ws2 = (((wi & 15) << 2) + (t & 3) + 2) & 63;
  const size_t src = ((size_t)b * 4096 + hs * 64 + ws2) * 384;
  float am[6], ap[6];
  float s1 = 0, s2 = 0, s3 = 0, s4 = 0;
#pragma unroll
  for (int j = 0; j < 6; ++j) {
    am[j] = xm[src + l + j * 64];
    ap[j] = xp[src + l + j * 64];
    s1 += am[j]; s2 += am[j] * am[j];
    s3 += ap[j]; s4 += ap[j] * ap[j];
  }
#pragma unroll
  for (int o = 1; o < 64; o <<= 1) {
    s1 += __shfl_xor(s1, o); s2 += __shfl_xor(s2, o);
    s3 += __shfl_xor(s3, o); s4 += __shfl_xor(s4, o);
  }
  const float mm = s1 * (1.f / 384.f);
  const float vm = s2 * (1.f / 384.f) - mm * mm;
  const float rm = rsqrtf(vm + 1e-5f);
  const float mp = s3 * (1.f / 384.f);
  const float vp = s4 * (1.f / 384.f) - mp * mp;
  const float rp = rsqrtf(vp + 1e-5f);
  unsigned short* qrow = q_ln + (size_t)dl * 384;
  unsigned short* kmrow = kv_ln + ((size_t)wl * 32 + t) * 384;
  unsigned short* kprow = kmrow + 16 * 384;
#pragma unroll
  for (int j = 0; j < 6; ++j) {
    int c = l + j * 64;
    float nm = (am[j] - mm) * rm;
    float np = (ap[j] - mp) * rp;
    qrow[c] = f2bf(nm * gq[c] + bq[c]);
    kmrow[c] = f2bf(nm * gkm[c] + bkm[c]);
    kprow[c] = f2bf(np * gkp[c] + bkp[c]);
  }
}

// ---------------------------------------------------------------------------
// Plain LN -> bf16 (for MLP input), full batch.
__global__ __launch_bounds__(256)
void ln_k(const float* __restrict__ x, const float* __restrict__ g,
          const float* __restrict__ b, unsigned short* __restrict__ o) {
  const int row = blockIdx.x * 4 + (threadIdx.x >> 6);
  const int l = threadIdx.x & 63;
  const float* xr = x + (size_t)row * 384;
  float a[6];
  float s1 = 0, s2 = 0;
#pragma unroll
  for (int j = 0; j < 6; ++j) {
    a[j] = xr[l + j * 64];
    s1 += a[j]; s2 += a[j] * a[j];
  }
#pragma unroll
  for (int of = 1; of < 64; of <<= 1) {
    s1 += __shfl_xor(s1, of); s2 += __shfl_xor(s2, of);
  }
  const float m = s1 * (1.f / 384.f);
  const float v = s2 * (1.f / 384.f) - m * m;
  const float r = rsqrtf(v + 1e-5f);
  unsigned short* orow = o + (size_t)row * 384;
#pragma unroll
  for (int j = 0; j < 6; ++j) {
    int c = l + j * 64;
    orow[c] = f2bf((a[j] - m) * r * g[c] + b[c]);
  }
}

// ---------------------------------------------------------------------------
// bf16 MFMA GEMM: C(MxN) = A(MxK) * Bt(NxK)^T + bias, templated epilogue.
// 128x128 tile, BK=32, 4 waves each computing 64x64 (m97 structure).
// XCD-aware block swizzle (T1): requires gridDim.x*gridDim.y % 8 == 0.
enum { EPI_BF16 = 0, EPI_KV = 1, EPI_WO = 2, EPI_GELU = 3, EPI_W2 = 4 };

template <int EPI>
__global__ __launch_bounds__(256, 2)
void gemm_k(const unsigned short* __restrict__ A,
            const unsigned short* __restrict__ Bt,
            const float* __restrict__ bias, const float* __restrict__ bias2,
            void* __restrict__ Cv, void* __restrict__ Cv2,
            const float* __restrict__ extra, int wbase, int M, int N, int K) {
  __shared__ unsigned short As[128 * 32];
  __shared__ unsigned short Bs[128 * 32];
  const int tid = threadIdx.x;
  const int l = tid & 63, wv = tid >> 6;
  const int lr = l & 15, og = l >> 4;

  // XCD swizzle: contiguous work-chunk per XCD (bijective when nwg%8==0)
  const unsigned gx = gridDim.x;
  const unsigned nwg = gx * gridDim.y;
  unsigned idx = blockIdx.y * gx + blockIdx.x;
  idx = (idx & 7u) * (nwg >> 3) + (idx >> 3);
  const int m0 = (int)(idx / gx) * 128, n0 = (int)(idx % gx) * 128;

  const int wm = (wv >> 1) * 64, wn = (wv & 1) * 64;

  f32x4 acc[4][4];
#pragma unroll
  for (int i = 0; i < 4; ++i)
#pragma unroll
    for (int j = 0; j < 4; ++j) acc[i][j] = (f32x4){0.f, 0.f, 0.f, 0.f};

  // staging: chunk=q*256+tid covers 16B; row=chunk/4, col=(chunk&3)*8
  const int r0 = tid >> 2, o0 = (tid & 3) * 8;
  const int r1 = (256 + tid) >> 2, o1 = ((256 + tid) & 3) * 8;
  const unsigned short* a0 = A + (size_t)(m0 + r0) * K + o0;
  const unsigned short* a1 = A + (size_t)(m0 + r1) * K + o1;
  const unsigned short* b0 = Bt + (size_t)(n0 + r0) * K + o0;
  const unsigned short* b1 = Bt + (size_t)(n0 + r1) * K + o1;
  unsigned short* lA0 = &As[(wv * 64) * 8];
  unsigned short* lA1 = &As[(256 + wv * 64) * 8];
  unsigned short* lB0 = &Bs[(wv * 64) * 8];
  unsigned short* lB1 = &Bs[(256 + wv * 64) * 8];

  for (int k0 = 0; k0 < K; k0 += 32) {
    GLD16(a0 + k0, lA0);
    GLD16(a1 + k0, lA1);
    GLD16(b0 + k0, lB0);
    GLD16(b1 + k0, lB1);
    __syncthreads();
    bf16x8 af[4], bfr[4];
#pragma unroll
    for (int i = 0; i < 4; ++i)
      af[i] = *(const bf16x8*)&As[(wm + i * 16 + lr) * 32 + og * 8];
#pragma unroll
    for (int j = 0; j < 4; ++j)
      bfr[j] = *(const bf16x8*)&Bs[(wn + j * 16 + lr) * 32 + og * 8];
#pragma unroll
    for (int i = 0; i < 4; ++i)
#pragma unroll
      for (int j = 0; j < 4; ++j)
        acc[i][j] = mfma16(af[i], bfr[j], acc[i][j]);
    __syncthreads();
  }

#pragma unroll
  for (int j = 0; j < 4; ++j) {
    const int c = n0 + wn + j * 16 + lr;
    const float bv_ =
        (EPI == EPI_KV) ? (c < 384 ? bias[c] : bias2[c - 384]) : bias[c];
#pragma unroll
    for (int i = 0; i < 4; ++i) {
      const int rb = m0 + wm + i * 16 + og * 4;
      if constexpr (EPI == EPI_BF16) {
        unsigned short* C = (unsigned short*)Cv;
#pragma unroll
        for (int r = 0; r < 4; ++r)
          C[(size_t)(rb + r) * N + c] = f2bf(acc[i][j][r] + bv_);
      } else if constexpr (EPI == EPI_KV) {
        if (c < 384) {  // K half: rows of Kb (local chunk, 384 cols)
          unsigned short* C = (unsigned short*)Cv;
#pragma unroll
          for (int r = 0; r < 4; ++r)
            C[(size_t)(rb + r) * 384 + c] = f2bf(acc[i][j][r] + bv_);
        } else {  // V half, transposed per head: Vt[((wl*6+h)*64+d)*32+u]
          unsigned short* C = (unsigned short*)Cv2;
          int cc = c - 384;
          int wdx = rb >> 5, u = rb & 31;
          size_t ix = (((size_t)wdx * 6 + (cc >> 6)) * 64 + (cc & 63)) * 32 + u;
          ushort4 v4;
          v4.x = f2bf(acc[i][j][0] + bv_);
          v4.y = f2bf(acc[i][j][1] + bv_);
          v4.z = f2bf(acc[i][j][2] + bv_);
          v4.w = f2bf(acc[i][j][3] + bv_);
          *(ushort4*)&C[ix] = v4;
        }
      } else if constexpr (EPI == EPI_WO) {
        // un-window + roll(+2,+2) + residual(x_main) -> fp32 x (global rows)
        float* C = (float*)Cv;
#pragma unroll
        for (int r = 0; r < 4; ++r) {
          int rr = rb + r;
          int wdx = (rr >> 4) + wbase, t = rr & 15;
          int b = wdx >> 8, wi = wdx & 255;
          int hd = (((wi >> 4) << 2) + (t >> 2) + 2) & 63;
          int wd = (((wi & 15) << 2) + (t & 3) + 2) & 63;
          size_t dst = ((size_t)b * 4096 + hd * 64 + wd) * 384 + c;
          C[dst] = extra[dst] + acc[i][j][r] + bv_;
        }
      } else if constexpr (EPI == EPI_GELU) {
        unsigned short* C = (unsigned short*)Cv;
#pragma unroll
        for (int r = 0; r < 4; ++r) {
          float v = acc[i][j][r] + bv_;
          v = 0.5f * v * (1.f + erff(v * 0.70710678118654752f));
          C[(size_t)(rb + r) * N + c] = f2bf(v);
        }
      } else {  // EPI_W2: residual from extra (same offset), fp32 out
        float* C = (float*)Cv;
#pragma unroll
        for (int r = 0; r < 4; ++r) {
          size_t ix = (size_t)(rb + r) * N + c;
          C[ix] = extra[ix] + acc[i][j][r] + bv_;
        }
      }
    }
  }
}

// ---------------------------------------------------------------------------
// Attention: one block per window (grid 2048/chunk), 6 waves = 6 heads.
// S_T = K*Q^T via mfma (softmax over keys = column reduce, 2 shuffles),
// mask analytic from window coords, P repacked via per-wave LDS, PV via
// mfma with pre-transposed V.
__global__ __launch_bounds__(384)
void attn_k(const unsigned short* __restrict__ Q,
            const unsigned short* __restrict__ K,
            const unsigned short* __restrict__ Vt,
            unsigned short* __restrict__ O, int wbase) {
  __shared__ unsigned short P_lds[6][16][32];
  const int wl = blockIdx.x;
  const int h = threadIdx.x >> 6, l = threadIdx.x & 63;
  const int lr = l & 15, og = l >> 4;
  const int wi = (wbase + wl) & 255;
  const int wh4 = (wi >> 4) << 2, ww4 = (wi & 15) << 2;

  auto rid = [&](int t) -> int {
    int hp = wh4 + (t >> 2), wp = ww4 + (t & 3);
    int rh = hp < 60 ? 0 : (hp < 62 ? 1 : 2);
    int rw = wp < 60 ? 0 : (wp < 62 ? 1 : 2);
    return rh * 3 + rw;
  };
  const int ridq = rid(lr);

  const size_t qbase = ((size_t)wl * 16 + lr) * 384 + h * 64 + og * 8;
  bf16x8 qf0 = *(const bf16x8*)&Q[qbase];
  bf16x8 qf1 = *(const bf16x8*)&Q[qbase + 32];
  const size_t kbase = ((size_t)wl * 32 + lr) * 384 + h * 64 + og * 8;
  bf16x8 kf00 = *(const bf16x8*)&K[kbase];
  bf16x8 kf01 = *(const bf16x8*)&K[kbase + 32];
  bf16x8 kf10 = *(const bf16x8*)&K[kbase + 16 * 384];
  bf16x8 kf11 = *(const bf16x8*)&K[kbase + 16 * 384 + 32];

  f32x4 s0 = (f32x4){0.f, 0.f, 0.f, 0.f}, s1 = (f32x4){0.f, 0.f, 0.f, 0.f};
  s0 = mfma16(kf00, qf0, s0);
  s0 = mfma16(kf01, qf1, s0);
  s1 = mfma16(kf10, qf0, s1);
  s1 = mfma16(kf11, qf1, s1);

  // lane holds S_T[u][t]: t=lr (query), u = og*4+r (km) / 16+og*4+r (kp)
  float p[8];
  float mx = -1e30f;
#pragma unroll
  for (int r = 0; r < 4; ++r) {
    float msk = (rid(og * 4 + r) == ridq) ? 0.f : -100.f;
    p[r] = s0[r] * 0.125f + msk;
    p[r + 4] = s1[r] * 0.125f + msk;
    mx = fmaxf(mx, fmaxf(p[r], p[r + 4]));
  }
  mx = fmaxf(mx, __shfl_xor(mx, 16));
  mx = fmaxf(mx, __shfl_xor(mx, 32));
  float sum = 0.f;
#pragma unroll
  for (int r = 0; r < 8; ++r) {
    p[r] = __expf(p[r] - mx);
    sum += p[r];
  }
  sum += __shfl_xor(sum, 16);
  sum += __shfl_xor(sum, 32);
  const float inv = 1.f / sum;

  uint2 pk;
  pk.x = (unsigned)f2bf(p[0] * inv) | ((unsigned)f2bf(p[1] * inv) << 16);
  pk.y = (unsigned)f2bf(p[2] * inv) | ((unsigned)f2bf(p[3] * inv) << 16);
  *(uint2*)&P_lds[h][lr][og * 4] = pk;
  pk.x = (unsigned)f2bf(p[4] * inv) | ((unsigned)f2bf(p[5] * inv) << 16);
  pk.y = (unsigned)f2bf(p[6] * inv) | ((unsigned)f2bf(p[7] * inv) << 16);
  *(uint2*)&P_lds[h][lr][16 + og * 4] = pk;

  bf16x8 pf = *(const bf16x8*)&P_lds[h][lr][og * 8];

  const size_t vbase = (((size_t)wl * 6 + h) * 64 + lr) * 32 + og * 8;
  f32x4 o4[4];
#pragma unroll
  for (int f = 0; f < 4; ++f) {
    bf16x8 vf = *(const bf16x8*)&Vt[vbase + (size_t)f * 16 * 32];
    o4[f] = mfma16(pf, vf, (f32x4){0.f, 0.f, 0.f, 0.f});
  }
#pragma unroll
  for (int f = 0; f < 4; ++f)
#pragma unroll
    for (int r = 0; r < 4; ++r)
      O[((size_t)wl * 16 + og * 4 + r) * 384 + h * 64 + f * 16 + lr] =
          f2bf(o4[f][r]);
}

// ---------------------------------------------------------------------------
extern "C" void kernel_launch(void* const* d_in, const int* in_sizes, int n_in,
                              void* d_out, int out_size, void* d_ws,
                              size_t ws_size, hipStream_t stream) {
  const float* x_main = (const float*)d_in[0];
  const float* x_mpmt = (const float*)d_in[1];
  const float* g_q = (const float*)d_in[2];
  const float* b_q = (const float*)d_in[3];
  const float* g_km = (const float*)d_in[4];
  const float* b_km = (const float*)d_in[5];
  const float* g_kp = (const float*)d_in[6];
  const float* b_kp = (const float*)d_in[7];
  const float* Wq = (const float*)d_in[8];
  const float* bq = (const float*)d_in[9];
  const float* Wk = (const float*)d_in[10];
  const float* bk = (const float*)d_in[11];
  const float* Wv = (const float*)d_in[12];
  const float* bv = (const float*)d_in[13];
  const float* Wo = (const float*)d_in[14];
  const float* bo = (const float*)d_in[15];
  const float* g_mlp = (const float*)d_in[16];
  const float* b_mlp = (const float*)d_in[17];
  const float* W1 = (const float*)d_in[18];
  const float* b1 = (const float*)d_in[19];
  const float* W2 = (const float*)d_in[20];
  const float* b2 = (const float*)d_in[21];

  char* ws = (char*)d_ws;
  // ws layout (bytes), peak 154,533,888 (~147.4 MiB):
  //   [0,        25165824)  q_ln chunk  -> attn_out chunk -> (with next) xm
  //   [25165824, 50331648)  Qb chunk                       -> (with prev) xm
  //   [50331648, 100663296) Kb chunk    -> H half
  //   [100663296,150994944) Vtb chunk   -> H half (upper part)
  //   [150994944,154533888) bf16 weights (Wq|Wk|Wv|Wo|W1|W2, K-major)
  // kv_ln chunks live in d_out halves (dead before Wo writes that half).
  unsigned short* q_ln = (unsigned short*)(ws + 0);
  unsigned short* Qb = (unsigned short*)(ws + 25165824ull);
  unsigned short* Kb = (unsigned short*)(ws + 50331648ull);
  unsigned short* Vtb = (unsigned short*)(ws + 100663296ull);
  unsigned short* attn_out = q_ln;
  unsigned short* xm = (unsigned short*)(ws + 0);       // 50.3 MB
  unsigned short* Hb = (unsigned short*)(ws + 50331648ull);  // 100.7 MB
  unsigned short* wt = (unsigned short*)(ws + 150994944ull);
  unsigned short* Wqt = wt + 0;
  unsigned short* Wkvt = wt + 147456;  // Wk^T rows 0..383, Wv^T rows 384..767
  unsigned short* Wot = wt + 442368;
  unsigned short* W1t = wt + 589824;
  unsigned short* W2t = wt + 1179648;
  float* xout = (float*)d_out;

  // 1. all weight transposes (fp32 -> bf16, K-major) in one launch
  wtrans_all<<<6912, 256, 0, stream>>>(Wq, Wk, Wv, Wo, W1, W2, wt);

  // 2-6. attention pipeline in two chunks of 2048 windows (8 batches each)
  for (int c = 0; c < 2; ++c) {
    const int wbase = c * 2048;
    unsigned short* kvl =
        (unsigned short*)((char*)d_out + (size_t)c * 50331648ull);

    ln_win_k<<<8192, 256, 0, stream>>>(x_main, x_mpmt, g_q, b_q, g_km, b_km,
                                       g_kp, b_kp, q_ln, kvl, wbase);

    gemm_k<EPI_BF16><<<dim3(3, 256), 256, 0, stream>>>(
        q_ln, Wqt, bq, nullptr, Qb, nullptr, nullptr, 0, 32768, 384, 384);

    gemm_k<EPI_KV><<<dim3(6, 512), 256, 0, stream>>>(
        kvl, Wkvt, bk, bv, Kb, Vtb, nullptr, 0, 65536, 768, 384);

    attn_k<<<2048, 384, 0, stream>>>(Qb, Kb, Vtb, attn_out, wbase);

    gemm_k<EPI_WO><<<dim3(3, 256), 256, 0, stream>>>(
        attn_out, Wot, bo, nullptr, xout, nullptr, x_main, wbase, 32768, 384,
        384);
  }

  // 7. LN for MLP (full batch)
  ln_k<<<16384, 256, 0, stream>>>(xout, g_mlp, b_mlp, xm);

  // 8-9. MLP in two row-halves, reusing one 100.7MB hidden buffer
  for (int hhalf = 0; hhalf < 2; ++hhalf) {
    const size_t ro = (size_t)hhalf * 32768;
    gemm_k<EPI_GELU><<<dim3(12, 256), 256, 0, stream>>>(
        xm + ro * 384, W1t, b1, nullptr, Hb, nullptr, nullptr, 0, 32768, 1536,
        384);
    gemm_k<EPI_W2><<<dim3(3, 256), 256, 0, stream>>>(
        Hb, W2t, b2, nullptr, xout + ro * 384, nullptr, xout + ro * 384, 0,
        32768, 384, 1536);
  }
}

// Round 5
// 823.438 us; speedup vs baseline: 1.2128x; 1.2128x over previous
//
#include <hip/hip_runtime.h>
#include <cstdint>
#include <cstddef>

#define DEVI __device__ __forceinline__

typedef __attribute__((ext_vector_type(8))) short bf16x8;
typedef __attribute__((ext_vector_type(4))) float f32x4;

DEVI unsigned short f2bf(float f) {
  unsigned u = __builtin_bit_cast(unsigned, f);
  u += 0x7fffu + ((u >> 16) & 1u);
  return (unsigned short)(u >> 16);
}

DEVI f32x4 mfma16(bf16x8 a, bf16x8 b, f32x4 c) {
  return __builtin_amdgcn_mfma_f32_16x16x32_bf16(a, b, c, 0, 0, 0);
}

#define GLD16(g, l) __builtin_amdgcn_global_load_lds( \
    (const __attribute__((address_space(1))) unsigned int*)(g), \
    (__attribute__((address_space(3))) unsigned int*)(l), 16, 0, 0)

// ---------------------------------------------------------------------------
// Weight transposes, LDS-tiled (coalesced read AND write):
// W (K x N, fp32) -> Wt (N x K, bf16), all 6 matrices concatenated.
// 32x32 tiles; 4x144 + 2x576 = 1728 tiles total.
__global__ __launch_bounds__(256)
void wtrans_all(const float* __restrict__ Wq, const float* __restrict__ Wk,
                const float* __restrict__ Wv, const float* __restrict__ Wo,
                const float* __restrict__ W1, const float* __restrict__ W2,
                unsigned short* __restrict__ out) {
  __shared__ float tl[32][33];
  int tu = blockIdx.x;
  const float* W;
  int K, N, obase;
  if (tu < 576) {
    int m = tu / 144;
    W = (m == 0) ? Wq : (m == 1) ? Wk : (m == 2) ? Wv : Wo;
    K = 384; N = 384; obase = m * 147456; tu -= m * 144;
  } else if (tu < 1152) {
    W = W1; K = 384; N = 1536; obase = 589824; tu -= 576;
  } else {
    W = W2; K = 1536; N = 384; obase = 1179648; tu -= 1152;
  }
  const int ktiles = K >> 5;
  const int tn = tu / ktiles, tk = tu - tn * ktiles;
  const int c = threadIdx.x & 31, rq = threadIdx.x >> 5;
#pragma unroll
  for (int ph = 0; ph < 4; ++ph) {
    int kk = tk * 32 + ph * 8 + rq;
    tl[ph * 8 + rq][c] = W[(size_t)kk * N + tn * 32 + c];
  }
  __syncthreads();
#pragma unroll
  for (int ph = 0; ph < 4; ++ph) {
    int nn = tn * 32 + ph * 8 + rq;
    out[obase + (size_t)nn * K + tk * 32 + c] = f2bf(tl[c][ph * 8 + rq]);
  }
}

// ---------------------------------------------------------------------------
// Fused LN(q)/LN(km)/LN(kp) + roll(-2,-2) + window partition, one chunk of
// 2048 windows (32768 tokens). One wave per destination window-token.
__global__ __launch_bounds__(256)
void ln_win_k(const float* __restrict__ xm, const float* __restrict__ xp,
              const float* __restrict__ gq, const float* __restrict__ bq,
              const float* __restrict__ gkm, const float* __restrict__ bkm,
              const float* __restrict__ gkp, const float* __restrict__ bkp,
              unsigned short* __restrict__ q_ln,
              unsigned short* __restrict__ kv_ln, int wbase) {
  const int dl = blockIdx.x * 4 + (threadIdx.x >> 6);  // 0..32767
  const int l = threadIdx.x & 63;
  const int wl = dl >> 4, t = dl & 15;
  const int w = wbase + wl;
  const int b = w >> 8, wi = w & 255;
  const int hs = (((wi >> 4) << 2) + (t >> 2) + 2) & 63;
  const int ws2 = (((wi & 15) << 2) + (t & 3) + 2) & 63;
  const size_t src = ((size_t)b * 4096 + hs * 64 + ws2) * 384;
  float am[6], ap[6];
  float s1 = 0, s2 = 0, s3 = 0, s4 = 0;
#pragma unroll
  for (int j = 0; j < 6; ++j) {
    am[j] = xm[src + l + j * 64];
    ap[j] = xp[src + l + j * 64];
    s1 += am[j]; s2 += am[j] * am[j];
    s3 += ap[j]; s4 += ap[j] * ap[j];
  }
#pragma unroll
  for (int o = 1; o < 64; o <<= 1) {
    s1 += __shfl_xor(s1, o); s2 += __shfl_xor(s2, o);
    s3 += __shfl_xor(s3, o); s4 += __shfl_xor(s4, o);
  }
  const float mm = s1 * (1.f / 384.f);
  const float vm = s2 * (1.f / 384.f) - mm * mm;
  const float rm = rsqrtf(vm + 1e-5f);
  const float mp = s3 * (1.f / 384.f);
  const float vp = s4 * (1.f / 384.f) - mp * mp;
  const float rp = rsqrtf(vp + 1e-5f);
  unsigned short* qrow = q_ln + (size_t)dl * 384;
  unsigned short* kmrow = kv_ln + ((size_t)wl * 32 + t) * 384;
  unsigned short* kprow = kmrow + 16 * 384;
#pragma unroll
  for (int j = 0; j < 6; ++j) {
    int c = l + j * 64;
    float nm = (am[j] - mm) * rm;
    float np = (ap[j] - mp) * rp;
    qrow[c] = f2bf(nm * gq[c] + bq[c]);
    kmrow[c] = f2bf(nm * gkm[c] + bkm[c]);
    kprow[c] = f2bf(np * gkp[c] + bkp[c]);
  }
}

// ---------------------------------------------------------------------------
// Plain LN -> bf16 (for MLP input), full batch.
__global__ __launch_bounds__(256)
void ln_k(const float* __restrict__ x, const float* __restrict__ g,
          const float* __restrict__ b, unsigned short* __restrict__ o) {
  const int row = blockIdx.x * 4 + (threadIdx.x >> 6);
  const int l = threadIdx.x & 63;
  const float* xr = x + (size_t)row * 384;
  float a[6];
  float s1 = 0, s2 = 0;
#pragma unroll
  for (int j = 0; j < 6; ++j) {
    a[j] = xr[l + j * 64];
    s1 += a[j]; s2 += a[j] * a[j];
  }
#pragma unroll
  for (int of = 1; of < 64; of <<= 1) {
    s1 += __shfl_xor(s1, of); s2 += __shfl_xor(s2, of);
  }
  const float m = s1 * (1.f / 384.f);
  const float v = s2 * (1.f / 384.f) - m * m;
  const float r = rsqrtf(v + 1e-5f);
  unsigned short* orow = o + (size_t)row * 384;
#pragma unroll
  for (int j = 0; j < 6; ++j) {
    int c = l + j * 64;
    orow[c] = f2bf((a[j] - m) * r * g[c] + b[c]);
  }
}

// ---------------------------------------------------------------------------
// bf16 MFMA GEMM: C(MxN) = A(MxK) * Bt(NxK)^T + bias, templated epilogue.
// 128x128 tile, BK=32, 4 waves of 64x64. Double-buffered LDS (32 KB) with
// stage-before-compute: one barrier per K-step, vmcnt drain overlapped with
// ds_read+MFMA (T3-minimum recipe). XCD swizzle needs nwg % 8 == 0.
enum { EPI_BF16 = 0, EPI_KV = 1, EPI_WO = 2, EPI_GELU = 3, EPI_W2 = 4 };

template <int EPI>
__global__ __launch_bounds__(256, 2)
void gemm_k(const unsigned short* __restrict__ A,
            const unsigned short* __restrict__ Bt,
            const float* __restrict__ bias, const float* __restrict__ bias2,
            void* __restrict__ Cv, void* __restrict__ Cv2,
            const float* __restrict__ extra, int wbase, int M, int N, int K) {
  __shared__ unsigned short As[2][128 * 32];
  __shared__ unsigned short Bs[2][128 * 32];
  const int tid = threadIdx.x;
  const int l = tid & 63, wv = tid >> 6;
  const int lr = l & 15, og = l >> 4;

  // XCD swizzle: contiguous work-chunk per XCD (bijective when nwg%8==0)
  const unsigned gx = gridDim.x;
  const unsigned nwg = gx * gridDim.y;
  unsigned idx = blockIdx.y * gx + blockIdx.x;
  idx = (idx & 7u) * (nwg >> 3) + (idx >> 3);
  const int m0 = (int)(idx / gx) * 128, n0 = (int)(idx % gx) * 128;

  const int wm = (wv >> 1) * 64, wn = (wv & 1) * 64;

  f32x4 acc[4][4];
#pragma unroll
  for (int i = 0; i < 4; ++i)
#pragma unroll
    for (int j = 0; j < 4; ++j) acc[i][j] = (f32x4){0.f, 0.f, 0.f, 0.f};

  // staging: chunk=q*256+tid covers 16B; row=chunk/4, col=(chunk&3)*8.
  // LDS layout is linear in tid within each wave's 1 KiB slice (gld_lds
  // writes wave-uniform-base + lane*16).
  const int r0 = tid >> 2, o0 = (tid & 3) * 8;
  const unsigned short* a0 = A + (size_t)(m0 + r0) * K + o0;
  const unsigned short* a1 = a0 + (size_t)64 * K;
  const unsigned short* b0 = Bt + (size_t)(n0 + r0) * K + o0;
  const unsigned short* b1 = b0 + (size_t)64 * K;
  const int lo = wv * 512;  // shorts

  const int nk = K >> 5;
  // prologue: stage tile 0 into buf 0
  GLD16(a0, &As[0][lo]);
  GLD16(a1, &As[0][2048 + lo]);
  GLD16(b0, &Bs[0][lo]);
  GLD16(b1, &Bs[0][2048 + lo]);
  __syncthreads();

  for (int t = 0; t < nk; ++t) {
    const int cur = t & 1;
    if (t + 1 < nk) {  // stage next tile into the other buffer (early issue)
      const int k0 = (t + 1) << 5;
      GLD16(a0 + k0, &As[cur ^ 1][lo]);
      GLD16(a1 + k0, &As[cur ^ 1][2048 + lo]);
      GLD16(b0 + k0, &Bs[cur ^ 1][lo]);
      GLD16(b1 + k0, &Bs[cur ^ 1][2048 + lo]);
    }
    bf16x8 af[4], bfr[4];
#pragma unroll
    for (int i = 0; i < 4; ++i)
      af[i] = *(const bf16x8*)&As[cur][(wm + i * 16 + lr) * 32 + og * 8];
#pragma unroll
    for (int j = 0; j < 4; ++j)
      bfr[j] = *(const bf16x8*)&Bs[cur][(wn + j * 16 + lr) * 32 + og * 8];
#pragma unroll
    for (int i = 0; i < 4; ++i)
#pragma unroll
      for (int j = 0; j < 4; ++j)
        acc[i][j] = mfma16(af[i], bfr[j], acc[i][j]);
    __syncthreads();  // drains vmcnt (next tile) + syncs reads of cur
  }

  // ---- epilogue: i-outer / j-inner so each output row's 128B line is
  // written by consecutive stores (full-line write combining) ----
  float bvj[4];
#pragma unroll
  for (int j = 0; j < 4; ++j) {
    int c = n0 + wn + j * 16 + lr;
    bvj[j] = (EPI == EPI_KV) ? (c < 384 ? bias[c] : bias2[c - 384]) : bias[c];
  }
  const int cb = n0 + wn + lr;

  if constexpr (EPI == EPI_BF16) {
    unsigned short* C = (unsigned short*)Cv;
#pragma unroll
    for (int i = 0; i < 4; ++i) {
      const int rb = m0 + wm + i * 16 + og * 4;
#pragma unroll
      for (int r = 0; r < 4; ++r) {
        unsigned short* row = C + (size_t)(rb + r) * N + cb;
#pragma unroll
        for (int j = 0; j < 4; ++j) row[j * 16] = f2bf(acc[i][j][r] + bvj[j]);
      }
    }
  } else if constexpr (EPI == EPI_GELU) {
    unsigned short* C = (unsigned short*)Cv;
#pragma unroll
    for (int i = 0; i < 4; ++i) {
      const int rb = m0 + wm + i * 16 + og * 4;
#pragma unroll
      for (int r = 0; r < 4; ++r) {
        unsigned short* row = C + (size_t)(rb + r) * N + cb;
#pragma unroll
        for (int j = 0; j < 4; ++j) {
          float v = acc[i][j][r] + bvj[j];
          v = 0.5f * v * (1.f + erff(v * 0.70710678118654752f));
          row[j * 16] = f2bf(v);
        }
      }
    }
  } else if constexpr (EPI == EPI_WO) {
    // un-window + roll(+2,+2) + residual(x_main) -> fp32 x (global rows)
    float* C = (float*)Cv;
#pragma unroll
    for (int i = 0; i < 4; ++i) {
      const int rb = m0 + wm + i * 16 + og * 4;
#pragma unroll
      for (int r = 0; r < 4; ++r) {
        int rr = rb + r;
        int wdx = (rr >> 4) + wbase, t = rr & 15;
        int b = wdx >> 8, wi = wdx & 255;
        int hd = (((wi >> 4) << 2) + (t >> 2) + 2) & 63;
        int wd = (((wi & 15) << 2) + (t & 3) + 2) & 63;
        size_t dst = ((size_t)b * 4096 + hd * 64 + wd) * 384 + cb;
#pragma unroll
        for (int j = 0; j < 4; ++j)
          C[dst + j * 16] = extra[dst + j * 16] + acc[i][j][r] + bvj[j];
      }
    }
  } else if constexpr (EPI == EPI_W2) {
    float* C = (float*)Cv;
#pragma unroll
    for (int i = 0; i < 4; ++i) {
      const int rb = m0 + wm + i * 16 + og * 4;
#pragma unroll
      for (int r = 0; r < 4; ++r) {
        size_t ix = (size_t)(rb + r) * N + cb;
#pragma unroll
        for (int j = 0; j < 4; ++j)
          C[ix + j * 16] = extra[ix + j * 16] + acc[i][j][r] + bvj[j];
      }
    }
  } else {  // EPI_KV
    if (n0 + wn < 384) {  // K half (row-major 384-col buffer)
      unsigned short* C = (unsigned short*)Cv;
#pragma unroll
      for (int i = 0; i < 4; ++i) {
        const int rb = m0 + wm + i * 16 + og * 4;
#pragma unroll
        for (int r = 0; r < 4; ++r) {
          unsigned short* row = C + (size_t)(rb + r) * 384 + cb;
#pragma unroll
          for (int j = 0; j < 4; ++j)
            row[j * 16] = f2bf(acc[i][j][r] + bvj[j]);
        }
      }
    } else {  // V half, transposed per head: Vt[((wl*6+h)*64+d)*32+u]
      unsigned short* C = (unsigned short*)Cv2;
#pragma unroll
      for (int j = 0; j < 4; ++j) {
        const int cc = n0 + wn + j * 16 + lr - 384;
#pragma unroll
        for (int i = 0; i < 4; ++i) {
          const int rb = m0 + wm + i * 16 + og * 4;
          int wdx = rb >> 5, u = rb & 31;
          size_t ix = (((size_t)wdx * 6 + (cc >> 6)) * 64 + (cc & 63)) * 32 + u;
          ushort4 v4;
          v4.x = f2bf(acc[i][j][0] + bvj[j]);
          v4.y = f2bf(acc[i][j][1] + bvj[j]);
          v4.z = f2bf(acc[i][j][2] + bvj[j]);
          v4.w = f2bf(acc[i][j][3] + bvj[j]);
          *(ushort4*)&C[ix] = v4;
        }
      }
    }
  }
}

// ---------------------------------------------------------------------------
// Attention: one block per window (grid 2048/chunk), 6 waves = 6 heads.
// S_T = K*Q^T via mfma (softmax over keys = column reduce, 2 shuffles),
// analytic mask, P repacked via per-wave LDS, PV via mfma with
// pre-transposed V.
__global__ __launch_bounds__(384)
void attn_k(const unsigned short* __restrict__ Q,
            const unsigned short* __restrict__ K,
            const unsigned short* __restrict__ Vt,
            unsigned short* __restrict__ O, int wbase) {
  __shared__ unsigned short P_lds[6][16][32];
  const int wl = blockIdx.x;
  const int h = threadIdx.x >> 6, l = threadIdx.x & 63;
  const int lr = l & 15, og = l >> 4;
  const int wi = (wbase + wl) & 255;
  const int wh4 = (wi >> 4) << 2, ww4 = (wi & 15) << 2;

  auto rid = [&](int t) -> int {
    int hp = wh4 + (t >> 2), wp = ww4 + (t & 3);
    int rh = hp < 60 ? 0 : (hp < 62 ? 1 : 2);
    int rw = wp < 60 ? 0 : (wp < 62 ? 1 : 2);
    return rh * 3 + rw;
  };
  const int ridq = rid(lr);

  const size_t qbase = ((size_t)wl * 16 + lr) * 384 + h * 64 + og * 8;
  bf16x8 qf0 = *(const bf16x8*)&Q[qbase];
  bf16x8 qf1 = *(const bf16x8*)&Q[qbase + 32];
  const size_t kbase = ((size_t)wl * 32 + lr) * 384 + h * 64 + og * 8;
  bf16x8 kf00 = *(const bf16x8*)&K[kbase];
  bf16x8 kf01 = *(const bf16x8*)&K[kbase + 32];
  bf16x8 kf10 = *(const bf16x8*)&K[kbase + 16 * 384];
  bf16x8 kf11 = *(const bf16x8*)&K[kbase + 16 * 384 + 32];

  f32x4 s0 = (f32x4){0.f, 0.f, 0.f, 0.f}, s1 = (f32x4){0.f, 0.f, 0.f, 0.f};
  s0 = mfma16(kf00, qf0, s0);
  s0 = mfma16(kf01, qf1, s0);
  s1 = mfma16(kf10, qf0, s1);
  s1 = mfma16(kf11, qf1, s1);

  // lane holds S_T[u][t]: t=lr (query), u = og*4+r (km) / 16+og*4+r (kp)
  float p[8];
  float mx = -1e30f;
#pragma unroll
  for (int r = 0; r < 4; ++r) {
    float msk = (rid(og * 4 + r) == ridq) ? 0.f : -100.f;
    p[r] = s0[r] * 0.125f + msk;
    p[r + 4] = s1[r] * 0.125f + msk;
    mx = fmaxf(mx, fmaxf(p[r], p[r + 4]));
  }
  mx = fmaxf(mx, __shfl_xor(mx, 16));
  mx = fmaxf(mx, __shfl_xor(mx, 32));
  float sum = 0.f;
#pragma unroll
  for (int r = 0; r < 8; ++r) {
    p[r] = __expf(p[r] - mx);
    sum += p[r];
  }
  sum += __shfl_xor(sum, 16);
  sum += __shfl_xor(sum, 32);
  const float inv = 1.f / sum;

  uint2 pk;
  pk.x = (unsigned)f2bf(p[0] * inv) | ((unsigned)f2bf(p[1] * inv) << 16);
  pk.y = (unsigned)f2bf(p[2] * inv) | ((unsigned)f2bf(p[3] * inv) << 16);
  *(uint2*)&P_lds[h][lr][og * 4] = pk;
  pk.x = (unsigned)f2bf(p[4] * inv) | ((unsigned)f2bf(p[5] * inv) << 16);
  pk.y = (unsigned)f2bf(p[6] * inv) | ((unsigned)f2bf(p[7] * inv) << 16);
  *(uint2*)&P_lds[h][lr][16 + og * 4] = pk;

  bf16x8 pf = *(const bf16x8*)&P_lds[h][lr][og * 8];

  const size_t vbase = (((size_t)wl * 6 + h) * 64 + lr) * 32 + og * 8;
  f32x4 o4[4];
#pragma unroll
  for (int f = 0; f < 4; ++f) {
    bf16x8 vf = *(const bf16x8*)&Vt[vbase + (size_t)f * 16 * 32];
    o4[f] = mfma16(pf, vf, (f32x4){0.f, 0.f, 0.f, 0.f});
  }
#pragma unroll
  for (int f = 0; f < 4; ++f)
#pragma unroll
    for (int r = 0; r < 4; ++r)
      O[((size_t)wl * 16 + og * 4 + r) * 384 + h * 64 + f * 16 + lr] =
          f2bf(o4[f][r]);
}

// ---------------------------------------------------------------------------
extern "C" void kernel_launch(void* const* d_in, const int* in_sizes, int n_in,
                              void* d_out, int out_size, void* d_ws,
                              size_t ws_size, hipStream_t stream) {
  const float* x_main = (const float*)d_in[0];
  const float* x_mpmt = (const float*)d_in[1];
  const float* g_q = (const float*)d_in[2];
  const float* b_q = (const float*)d_in[3];
  const float* g_km = (const float*)d_in[4];
  const float* b_km = (const float*)d_in[5];
  const float* g_kp = (const float*)d_in[6];
  const float* b_kp = (const float*)d_in[7];
  const float* Wq = (const float*)d_in[8];
  const float* bq = (const float*)d_in[9];
  const float* Wk = (const float*)d_in[10];
  const float* bk = (const float*)d_in[11];
  const float* Wv = (const float*)d_in[12];
  const float* bv = (const float*)d_in[13];
  const float* Wo = (const float*)d_in[14];
  const float* bo = (const float*)d_in[15];
  const float* g_mlp = (const float*)d_in[16];
  const float* b_mlp = (const float*)d_in[17];
  const float* W1 = (const float*)d_in[18];
  const float* b1 = (const float*)d_in[19];
  const float* W2 = (const float*)d_in[20];
  const float* b2 = (const float*)d_in[21];

  char* ws = (char*)d_ws;
  // ws layout (bytes), peak 154,533,888 (~147.4 MiB) — proven to fit:
  //   [0,        25165824)  q_ln chunk  -> attn_out chunk -> (with next) xm
  //   [25165824, 50331648)  Qb chunk                       -> (with prev) xm
  //   [50331648, 100663296) Kb chunk    -> H half
  //   [100663296,150994944) Vtb chunk   -> H half (upper part)
  //   [150994944,154533888) bf16 weights (Wq|Wk|Wv|Wo|W1|W2, K-major)
  // kv_ln chunks live in d_out halves (dead before Wo writes that half).
  unsigned short* q_ln = (unsigned short*)(ws + 0);
  unsigned short* Qb = (unsigned short*)(ws + 25165824ull);
  unsigned short* Kb = (unsigned short*)(ws + 50331648ull);
  unsigned short* Vtb = (unsigned short*)(ws + 100663296ull);
  unsigned short* attn_out = q_ln;
  unsigned short* xm = (unsigned short*)(ws + 0);            // 50.3 MB
  unsigned short* Hb = (unsigned short*)(ws + 50331648ull);  // 100.7 MB
  unsigned short* wt = (unsigned short*)(ws + 150994944ull);
  unsigned short* Wqt = wt + 0;
  unsigned short* Wkvt = wt + 147456;  // Wk^T rows 0..383, Wv^T rows 384..767
  unsigned short* Wot = wt + 442368;
  unsigned short* W1t = wt + 589824;
  unsigned short* W2t = wt + 1179648;
  float* xout = (float*)d_out;

  // 1. all weight transposes (fp32 -> bf16, K-major), LDS-tiled
  wtrans_all<<<1728, 256, 0, stream>>>(Wq, Wk, Wv, Wo, W1, W2, wt);

  // 2-6. attention pipeline in two chunks of 2048 windows (8 batches each)
  for (int c = 0; c < 2; ++c) {
    const int wbase = c * 2048;
    unsigned short* kvl =
        (unsigned short*)((char*)d_out + (size_t)c * 50331648ull);

    ln_win_k<<<8192, 256, 0, stream>>>(x_main, x_mpmt, g_q, b_q, g_km, b_km,
                                       g_kp, b_kp, q_ln, kvl, wbase);

    gemm_k<EPI_BF16><<<dim3(3, 256), 256, 0, stream>>>(
        q_ln, Wqt, bq, nullptr, Qb, nullptr, nullptr, 0, 32768, 384, 384);

    gemm_k<EPI_KV><<<dim3(6, 512), 256, 0, stream>>>(
        kvl, Wkvt, bk, bv, Kb, Vtb, nullptr, 0, 65536, 768, 384);

    attn_k<<<2048, 384, 0, stream>>>(Qb, Kb, Vtb, attn_out, wbase);

    gemm_k<EPI_WO><<<dim3(3, 256), 256, 0, stream>>>(
        attn_out, Wot, bo, nullptr, xout, nullptr, x_main, wbase, 32768, 384,
        384);
  }

  // 7. LN for MLP (full batch)
  ln_k<<<16384, 256, 0, stream>>>(xout, g_mlp, b_mlp, xm);

  // 8-9. MLP in two row-halves, reusing one 100.7MB hidden buffer
  for (int hhalf = 0; hhalf < 2; ++hhalf) {
    const size_t ro = (size_t)hhalf * 32768;
    gemm_k<EPI_GELU><<<dim3(12, 256), 256, 0, stream>>>(
        xm + ro * 384, W1t, b1, nullptr, Hb, nullptr, nullptr, 0, 32768, 1536,
        384);
    gemm_k<EPI_W2><<<dim3(3, 256), 256, 0, stream>>>(
        Hb, W2t, b2, nullptr, xout + ro * 384, nullptr, xout + ro * 384, 0,
        32768, 384, 1536);
  }
}